// Round 5
// baseline (211.672 us; speedup 1.0000x reference)
//
#include <hip/hip_runtime.h>

#define BB 4
#define HH 512
#define WW 512
#define KK 7
#define PP 3
#define CC 256
#define RH 64                  // region height
#define RW 32                  // region width
#define SH (RH + 2 * PP)       // 70
#define SW (RW + 2 * PP)       // 38
#define NT 1024                // threads per block
#define NWAVE (NT / 64)        // 16
#define NREG (BB * (HH / RH) * (WW / RW))   // 512

// Scatter active-site linear index into dense idx_map (pre-filled with -1).
__global__ void smconv_scatter(const int* __restrict__ idx,
                               int* __restrict__ idx_map, int n) {
    int i = blockIdx.x * blockDim.x + threadIdx.x;
    if (i >= n) return;
    int b = idx[i * 3 + 0];
    int y = idx[i * 3 + 1];
    int x = idx[i * 3 + 2];
    idx_map[((size_t)b * HH + y) * WW + x] = i;
}

// Transpose weight (C, K, K) -> (K*K, C) so channel-major loads coalesce.
__global__ void smconv_wt(const float* __restrict__ w, float* __restrict__ w_t) {
    int i = blockIdx.x * blockDim.x + threadIdx.x;
    if (i >= KK * KK * CC) return;
    int tap = i / CC;
    int c = i - tap * CC;
    w_t[i] = w[c * KK * KK + tap];
}

// One block per 64x32 region (512 blocks = 2/CU). 16 waves; each wave keeps
// TWO sites in flight (independent acc chains -> 2x MLP). Tap broadcast via
// readlane (SGPR path, no ds_bpermute). Weights served from LDS.
__global__ void __launch_bounds__(NT)
smconv_conv_region(const float* __restrict__ feat,
                   const float* __restrict__ w_t,
                   const float* __restrict__ bias,
                   const int* __restrict__ idx_map,
                   float* __restrict__ out) {
    __shared__ int smap[SH * SW];                 // 10,640 B
    __shared__ unsigned short lst[RH * RW];       //  4,096 B
    __shared__ int wcnt[NWAVE];
    __shared__ float w_lds[KK * KK * CC];         // 50,176 B

    const int tid  = threadIdx.x;
    const int wave = tid >> 6;
    const int lane = tid & 63;

    // XCD-chunked swizzle: XCD k owns 64 contiguous regions (512x256 slab).
    const int r  = (blockIdx.x & 7) * 64 + (blockIdx.x >> 3);
    const int b  = r >> 7;              // 128 regions per batch
    const int rm = r & 127;
    const int rx = rm >> 3;             // 16 column strips
    const int ry = rm & 7;              // 8 row strips
    const int y0 = ry * RH;
    const int x0 = rx * RW;

    // Stage weights (tap, C) into LDS, coalesced float4.
    for (int i = tid; i < KK * KK * CC / 4; i += NT)
        ((float4*)w_lds)[i] = ((const float4*)w_t)[i];

    // Stage region+halo idx_map into LDS (-1 outside image).
    for (int i = tid; i < SH * SW; i += NT) {
        int gy = y0 + i / SW - PP;
        int gx = x0 + i % SW - PP;
        int v = -1;
        if (gy >= 0 && gy < HH && gx >= 0 && gx < WW)
            v = idx_map[((size_t)b * HH + gy) * WW + gx];
        smap[i] = v;
    }
    __syncthreads();

    // Build active-site list in deterministic scan order.
    int total = 0;
    for (int c = 0; c < RH * RW; c += NT) {
        int i = c + tid;
        int iy = i >> 5;
        int ix = i & (RW - 1);
        bool act = smap[(iy + PP) * SW + (ix + PP)] >= 0;
        unsigned long long bal = __ballot(act);
        if (lane == 0) wcnt[wave] = __popcll(bal);
        __syncthreads();
        int off = total;
        for (int w = 0; w < wave; ++w) off += wcnt[w];
        if (act)
            lst[off + __popcll(bal & ((1ull << lane) - 1))] = (unsigned short)i;
        int t2 = total;
        for (int w = 0; w < NWAVE; ++w) t2 += wcnt[w];
        total = t2;
        __syncthreads();
    }

    const int c4 = lane * 4;
    const int dy = lane / KK;   // tap row (lane < 49)
    const int dx = lane % KK;   // tap col
    const float4 bv = *(const float4*)(bias + c4);

    for (int e = wave; e < total; e += 2 * NWAVE) {
        const int eB = e + NWAVE;
        const bool hasB = eB < total;

        const int posA = lst[e];
        const int posB = hasB ? lst[eB] : posA;
        const int iyA = posA >> 5, ixA = posA & (RW - 1);
        const int iyB = posB >> 5, ixB = posB & (RW - 1);

        int nbA = -1, nbB = -1;
        if (lane < KK * KK) {
            nbA = smap[(iyA + dy) * SW + (ixA + dx)];
            nbB = smap[(iyB + dy) * SW + (ixB + dx)];
        }
        if (!hasB) nbB = -1;

        unsigned long long mA = __ballot(nbA >= 0);
        unsigned long long mB = __ballot(nbB >= 0);

        const int siteA = __builtin_amdgcn_readlane(nbA, PP * KK + PP);
        const int siteB = __builtin_amdgcn_readlane(nbB, PP * KK + PP);

        float4 accA = make_float4(0.f, 0.f, 0.f, 0.f);
        float4 accB = make_float4(0.f, 0.f, 0.f, 0.f);

        while (mA | mB) {
            // Peel up to 2 taps per site; dummies read row 0 (harmless).
            bool a0 = mA != 0;
            int tA0 = a0 ? __ffsll((long long)mA) - 1 : 0;
            if (a0) mA &= mA - 1;
            bool a1 = mA != 0;
            int tA1 = a1 ? __ffsll((long long)mA) - 1 : 0;
            if (a1) mA &= mA - 1;

            bool b0 = mB != 0;
            int tB0 = b0 ? __ffsll((long long)mB) - 1 : 0;
            if (b0) mB &= mB - 1;
            bool b1 = mB != 0;
            int tB1 = b1 ? __ffsll((long long)mB) - 1 : 0;
            if (b1) mB &= mB - 1;

            int nA0 = a0 ? __builtin_amdgcn_readlane(nbA, tA0) : 0;
            int nA1 = a1 ? __builtin_amdgcn_readlane(nbA, tA1) : 0;
            int nB0 = b0 ? __builtin_amdgcn_readlane(nbB, tB0) : 0;
            int nB1 = b1 ? __builtin_amdgcn_readlane(nbB, tB1) : 0;

            float4 fA0 = *(const float4*)(feat + (size_t)nA0 * CC + c4);
            float4 fA1 = *(const float4*)(feat + (size_t)nA1 * CC + c4);
            float4 fB0 = *(const float4*)(feat + (size_t)nB0 * CC + c4);
            float4 fB1 = *(const float4*)(feat + (size_t)nB1 * CC + c4);
            float4 wA0 = *(const float4*)(w_lds + tA0 * CC + c4);
            float4 wA1 = *(const float4*)(w_lds + tA1 * CC + c4);
            float4 wB0 = *(const float4*)(w_lds + tB0 * CC + c4);
            float4 wB1 = *(const float4*)(w_lds + tB1 * CC + c4);

            if (a0) {
                accA.x = fmaf(fA0.x, wA0.x, accA.x);
                accA.y = fmaf(fA0.y, wA0.y, accA.y);
                accA.z = fmaf(fA0.z, wA0.z, accA.z);
                accA.w = fmaf(fA0.w, wA0.w, accA.w);
            }
            if (a1) {
                accA.x = fmaf(fA1.x, wA1.x, accA.x);
                accA.y = fmaf(fA1.y, wA1.y, accA.y);
                accA.z = fmaf(fA1.z, wA1.z, accA.z);
                accA.w = fmaf(fA1.w, wA1.w, accA.w);
            }
            if (b0) {
                accB.x = fmaf(fB0.x, wB0.x, accB.x);
                accB.y = fmaf(fB0.y, wB0.y, accB.y);
                accB.z = fmaf(fB0.z, wB0.z, accB.z);
                accB.w = fmaf(fB0.w, wB0.w, accB.w);
            }
            if (b1) {
                accB.x = fmaf(fB1.x, wB1.x, accB.x);
                accB.y = fmaf(fB1.y, wB1.y, accB.y);
                accB.z = fmaf(fB1.z, wB1.z, accB.z);
                accB.w = fmaf(fB1.w, wB1.w, accB.w);
            }
        }

        float4 oA = make_float4(accA.x + bv.x, accA.y + bv.y,
                                accA.z + bv.z, accA.w + bv.w);
        *(float4*)(out + (size_t)siteA * CC + c4) = oA;
        if (hasB) {
            float4 oB = make_float4(accB.x + bv.x, accB.y + bv.y,
                                    accB.z + bv.z, accB.w + bv.w);
            *(float4*)(out + (size_t)siteB * CC + c4) = oB;
        }
    }
}

extern "C" void kernel_launch(void* const* d_in, const int* in_sizes, int n_in,
                              void* d_out, int out_size, void* d_ws, size_t ws_size,
                              hipStream_t stream) {
    const float* feat = (const float*)d_in[0];
    const int*   idx  = (const int*)d_in[1];
    const float* w    = (const float*)d_in[2];
    const float* bias = (const float*)d_in[3];
    float* out = (float*)d_out;

    const int n = in_sizes[0] / CC;  // number of active sites

    int*   idx_map = (int*)d_ws;
    float* w_t     = (float*)((char*)d_ws + (size_t)BB * HH * WW * sizeof(int));

    // 1) idx_map = -1
    hipMemsetAsync(idx_map, 0xFF, (size_t)BB * HH * WW * sizeof(int), stream);
    // 2) scatter site ids
    smconv_scatter<<<(n + 255) / 256, 256, 0, stream>>>(idx, idx_map, n);
    // 3) transpose weights to (tap, C)
    smconv_wt<<<(KK * KK * CC + 255) / 256, 256, 0, stream>>>(w, w_t);
    // 4) region conv: one block per 64x32 region, 512 blocks = 2/CU
    smconv_conv_region<<<NREG, NT, 0, stream>>>(feat, w_t, bias, idx_map, out);
}

// Round 6
// 210.816 us; speedup vs baseline: 1.0041x; 1.0041x over previous
//
#include <hip/hip_runtime.h>

#define BB 4
#define HH 512
#define WW 512
#define KK 7
#define PP 3
#define CC 256
#define RH 64                  // region height
#define RW 32                  // region width
#define SH (RH + 2 * PP)       // 70
#define SW (RW + 2 * PP)       // 38
#define NT 1024                // threads per block
#define NWAVE (NT / 64)        // 16
#define NREG (BB * (HH / RH) * (WW / RW))   // 512

// Scatter active-site linear index into dense idx_map (pre-filled with -1).
__global__ void smconv_scatter(const int* __restrict__ idx,
                               int* __restrict__ idx_map, int n) {
    int i = blockIdx.x * blockDim.x + threadIdx.x;
    if (i >= n) return;
    int b = idx[i * 3 + 0];
    int y = idx[i * 3 + 1];
    int x = idx[i * 3 + 2];
    idx_map[((size_t)b * HH + y) * WW + x] = i;
}

// Transpose weight (C, K, K) -> (K*K, C) so channel-major loads coalesce.
__global__ void smconv_wt(const float* __restrict__ w, float* __restrict__ w_t) {
    int i = blockIdx.x * blockDim.x + threadIdx.x;
    if (i >= KK * KK * CC) return;
    int tap = i / CC;
    int c = i - tap * CC;
    w_t[i] = w[c * KK * KK + tap];
}

// One block per 64x32 region (512 blocks = 2/CU). 16 waves, ONE site per wave
// (tight reuse window); first peel group is 8 deep (dummy-padded), then 4-deep
// groups. Neighbor ids broadcast via readlane (SGPR base path). Weights in LDS.
__global__ void __launch_bounds__(NT, 8)
smconv_conv_region(const float* __restrict__ feat,
                   const float* __restrict__ w_t,
                   const float* __restrict__ bias,
                   const int* __restrict__ idx_map,
                   float* __restrict__ out) {
    __shared__ int smap[SH * SW];                 // 10,640 B
    __shared__ unsigned short lst[RH * RW];       //  4,096 B
    __shared__ int wcnt[NWAVE];
    __shared__ float w_lds[KK * KK * CC];         // 50,176 B

    const int tid  = threadIdx.x;
    const int wave = tid >> 6;
    const int lane = tid & 63;

    // XCD-chunked swizzle: XCD k owns 64 contiguous regions (512x256 slab).
    const int r  = (blockIdx.x & 7) * 64 + (blockIdx.x >> 3);
    const int b  = r >> 7;              // 128 regions per batch
    const int rm = r & 127;
    const int rx = rm >> 3;             // 16 column strips
    const int ry = rm & 7;              // 8 row strips
    const int y0 = ry * RH;
    const int x0 = rx * RW;

    // Stage weights (tap, C) into LDS, coalesced float4.
    for (int i = tid; i < KK * KK * CC / 4; i += NT)
        ((float4*)w_lds)[i] = ((const float4*)w_t)[i];

    // Stage region+halo idx_map into LDS (-1 outside image).
    for (int i = tid; i < SH * SW; i += NT) {
        int gy = y0 + i / SW - PP;
        int gx = x0 + i % SW - PP;
        int v = -1;
        if (gy >= 0 && gy < HH && gx >= 0 && gx < WW)
            v = idx_map[((size_t)b * HH + gy) * WW + gx];
        smap[i] = v;
    }
    __syncthreads();

    // Build active-site list in deterministic scan order.
    int total = 0;
    for (int c = 0; c < RH * RW; c += NT) {
        int i = c + tid;
        int iy = i >> 5;
        int ix = i & (RW - 1);
        bool act = smap[(iy + PP) * SW + (ix + PP)] >= 0;
        unsigned long long bal = __ballot(act);
        if (lane == 0) wcnt[wave] = __popcll(bal);
        __syncthreads();
        int off = total;
        for (int w = 0; w < wave; ++w) off += wcnt[w];
        if (act)
            lst[off + __popcll(bal & ((1ull << lane) - 1))] = (unsigned short)i;
        int t2 = total;
        for (int w = 0; w < NWAVE; ++w) t2 += wcnt[w];
        total = t2;
        __syncthreads();
    }

    const int c4 = lane * 4;
    const int dy = lane / KK;   // tap row (lane < 49)
    const int dx = lane % KK;   // tap col
    const float4 bv = *(const float4*)(bias + c4);

    for (int e = wave; e < total; e += NWAVE) {
        const int pos = lst[e];
        const int iy = pos >> 5;
        const int ix = pos & (RW - 1);

        int nb = -1;
        if (lane < KK * KK)
            nb = smap[(iy + dy) * SW + (ix + dx)];

        const int site = __builtin_amdgcn_readlane(nb, PP * KK + PP);
        unsigned long long mask = __ballot(nb >= 0);

        float4 acc = make_float4(0.f, 0.f, 0.f, 0.f);

        // ---- First group: peel up to 8 taps (dummies repeat t0, L1-hot) ----
        {
            int t0 = __ffsll((long long)mask) - 1; mask &= mask - 1;
            bool h1 = mask != 0;
            int t1 = h1 ? __ffsll((long long)mask) - 1 : t0; if (h1) mask &= mask - 1;
            bool h2 = mask != 0;
            int t2 = h2 ? __ffsll((long long)mask) - 1 : t0; if (h2) mask &= mask - 1;
            bool h3 = mask != 0;
            int t3 = h3 ? __ffsll((long long)mask) - 1 : t0; if (h3) mask &= mask - 1;
            bool h4 = mask != 0;
            int t4 = h4 ? __ffsll((long long)mask) - 1 : t0; if (h4) mask &= mask - 1;
            bool h5 = mask != 0;
            int t5 = h5 ? __ffsll((long long)mask) - 1 : t0; if (h5) mask &= mask - 1;
            bool h6 = mask != 0;
            int t6 = h6 ? __ffsll((long long)mask) - 1 : t0; if (h6) mask &= mask - 1;
            bool h7 = mask != 0;
            int t7 = h7 ? __ffsll((long long)mask) - 1 : t0; if (h7) mask &= mask - 1;

            int n0 = __builtin_amdgcn_readlane(nb, t0);
            int n1 = __builtin_amdgcn_readlane(nb, t1);
            int n2 = __builtin_amdgcn_readlane(nb, t2);
            int n3 = __builtin_amdgcn_readlane(nb, t3);
            int n4 = __builtin_amdgcn_readlane(nb, t4);
            int n5 = __builtin_amdgcn_readlane(nb, t5);
            int n6 = __builtin_amdgcn_readlane(nb, t6);
            int n7 = __builtin_amdgcn_readlane(nb, t7);

            float4 f0 = *(const float4*)(feat + (size_t)n0 * CC + c4);
            float4 f1 = *(const float4*)(feat + (size_t)n1 * CC + c4);
            float4 f2 = *(const float4*)(feat + (size_t)n2 * CC + c4);
            float4 f3 = *(const float4*)(feat + (size_t)n3 * CC + c4);
            float4 f4 = *(const float4*)(feat + (size_t)n4 * CC + c4);
            float4 f5 = *(const float4*)(feat + (size_t)n5 * CC + c4);
            float4 f6 = *(const float4*)(feat + (size_t)n6 * CC + c4);
            float4 f7 = *(const float4*)(feat + (size_t)n7 * CC + c4);

            // Consume in order: compiler emits progressive vmcnt waits.
            {
                float4 wv = *(const float4*)(w_lds + t0 * CC + c4);
                acc.x = fmaf(f0.x, wv.x, acc.x); acc.y = fmaf(f0.y, wv.y, acc.y);
                acc.z = fmaf(f0.z, wv.z, acc.z); acc.w = fmaf(f0.w, wv.w, acc.w);
            }
            if (h1) {
                float4 wv = *(const float4*)(w_lds + t1 * CC + c4);
                acc.x = fmaf(f1.x, wv.x, acc.x); acc.y = fmaf(f1.y, wv.y, acc.y);
                acc.z = fmaf(f1.z, wv.z, acc.z); acc.w = fmaf(f1.w, wv.w, acc.w);
            }
            if (h2) {
                float4 wv = *(const float4*)(w_lds + t2 * CC + c4);
                acc.x = fmaf(f2.x, wv.x, acc.x); acc.y = fmaf(f2.y, wv.y, acc.y);
                acc.z = fmaf(f2.z, wv.z, acc.z); acc.w = fmaf(f2.w, wv.w, acc.w);
            }
            if (h3) {
                float4 wv = *(const float4*)(w_lds + t3 * CC + c4);
                acc.x = fmaf(f3.x, wv.x, acc.x); acc.y = fmaf(f3.y, wv.y, acc.y);
                acc.z = fmaf(f3.z, wv.z, acc.z); acc.w = fmaf(f3.w, wv.w, acc.w);
            }
            if (h4) {
                float4 wv = *(const float4*)(w_lds + t4 * CC + c4);
                acc.x = fmaf(f4.x, wv.x, acc.x); acc.y = fmaf(f4.y, wv.y, acc.y);
                acc.z = fmaf(f4.z, wv.z, acc.z); acc.w = fmaf(f4.w, wv.w, acc.w);
            }
            if (h5) {
                float4 wv = *(const float4*)(w_lds + t5 * CC + c4);
                acc.x = fmaf(f5.x, wv.x, acc.x); acc.y = fmaf(f5.y, wv.y, acc.y);
                acc.z = fmaf(f5.z, wv.z, acc.z); acc.w = fmaf(f5.w, wv.w, acc.w);
            }
            if (h6) {
                float4 wv = *(const float4*)(w_lds + t6 * CC + c4);
                acc.x = fmaf(f6.x, wv.x, acc.x); acc.y = fmaf(f6.y, wv.y, acc.y);
                acc.z = fmaf(f6.z, wv.z, acc.z); acc.w = fmaf(f6.w, wv.w, acc.w);
            }
            if (h7) {
                float4 wv = *(const float4*)(w_lds + t7 * CC + c4);
                acc.x = fmaf(f7.x, wv.x, acc.x); acc.y = fmaf(f7.y, wv.y, acc.y);
                acc.z = fmaf(f7.z, wv.z, acc.z); acc.w = fmaf(f7.w, wv.w, acc.w);
            }
        }

        // ---- Continuation: 4-deep groups (rare; avg 1.4 taps remain) ----
        while (mask) {
            int t0 = __ffsll((long long)mask) - 1; mask &= mask - 1;
            bool h1 = mask != 0;
            int t1 = h1 ? __ffsll((long long)mask) - 1 : t0; if (h1) mask &= mask - 1;
            bool h2 = mask != 0;
            int t2 = h2 ? __ffsll((long long)mask) - 1 : t0; if (h2) mask &= mask - 1;
            bool h3 = mask != 0;
            int t3 = h3 ? __ffsll((long long)mask) - 1 : t0; if (h3) mask &= mask - 1;

            int n0 = __builtin_amdgcn_readlane(nb, t0);
            int n1 = __builtin_amdgcn_readlane(nb, t1);
            int n2 = __builtin_amdgcn_readlane(nb, t2);
            int n3 = __builtin_amdgcn_readlane(nb, t3);

            float4 f0 = *(const float4*)(feat + (size_t)n0 * CC + c4);
            float4 f1 = *(const float4*)(feat + (size_t)n1 * CC + c4);
            float4 f2 = *(const float4*)(feat + (size_t)n2 * CC + c4);
            float4 f3 = *(const float4*)(feat + (size_t)n3 * CC + c4);

            {
                float4 wv = *(const float4*)(w_lds + t0 * CC + c4);
                acc.x = fmaf(f0.x, wv.x, acc.x); acc.y = fmaf(f0.y, wv.y, acc.y);
                acc.z = fmaf(f0.z, wv.z, acc.z); acc.w = fmaf(f0.w, wv.w, acc.w);
            }
            if (h1) {
                float4 wv = *(const float4*)(w_lds + t1 * CC + c4);
                acc.x = fmaf(f1.x, wv.x, acc.x); acc.y = fmaf(f1.y, wv.y, acc.y);
                acc.z = fmaf(f1.z, wv.z, acc.z); acc.w = fmaf(f1.w, wv.w, acc.w);
            }
            if (h2) {
                float4 wv = *(const float4*)(w_lds + t2 * CC + c4);
                acc.x = fmaf(f2.x, wv.x, acc.x); acc.y = fmaf(f2.y, wv.y, acc.y);
                acc.z = fmaf(f2.z, wv.z, acc.z); acc.w = fmaf(f2.w, wv.w, acc.w);
            }
            if (h3) {
                float4 wv = *(const float4*)(w_lds + t3 * CC + c4);
                acc.x = fmaf(f3.x, wv.x, acc.x); acc.y = fmaf(f3.y, wv.y, acc.y);
                acc.z = fmaf(f3.z, wv.z, acc.z); acc.w = fmaf(f3.w, wv.w, acc.w);
            }
        }

        float4 o = make_float4(acc.x + bv.x, acc.y + bv.y,
                               acc.z + bv.z, acc.w + bv.w);
        *(float4*)(out + (size_t)site * CC + c4) = o;
    }
}

extern "C" void kernel_launch(void* const* d_in, const int* in_sizes, int n_in,
                              void* d_out, int out_size, void* d_ws, size_t ws_size,
                              hipStream_t stream) {
    const float* feat = (const float*)d_in[0];
    const int*   idx  = (const int*)d_in[1];
    const float* w    = (const float*)d_in[2];
    const float* bias = (const float*)d_in[3];
    float* out = (float*)d_out;

    const int n = in_sizes[0] / CC;  // number of active sites

    int*   idx_map = (int*)d_ws;
    float* w_t     = (float*)((char*)d_ws + (size_t)BB * HH * WW * sizeof(int));

    // 1) idx_map = -1
    hipMemsetAsync(idx_map, 0xFF, (size_t)BB * HH * WW * sizeof(int), stream);
    // 2) scatter site ids
    smconv_scatter<<<(n + 255) / 256, 256, 0, stream>>>(idx, idx_map, n);
    // 3) transpose weights to (tap, C)
    smconv_wt<<<(KK * KK * CC + 255) / 256, 256, 0, stream>>>(w, w_t);
    // 4) region conv: one block per 64x32 region, 512 blocks = 2/CU
    smconv_conv_region<<<NREG, NT, 0, stream>>>(feat, w_t, bias, idx_map, out);
}